// Round 4
// baseline (45.004 us; speedup 1.0000x reference)
//
#include <hip/hip_runtime.h>

#define BB 2
#define NN1 512
#define NN2 512
#define DD 128
#define TS 32          // cross tile: 32x32 (n,m) per block
#define SXPAD 132      // row stride in floats: 16B-aligned, rows shift banks

// ---- Trans-free GELU ----------------------------------------------------
// gelu(s) = s*Phi(s) = s*(0.5 + 0.5*erf(s/sqrt2))
//         = s*(0.5 + c*Q(c*c)) with clamp c = med3(s,-3,3)
// Q(t) = (1/sqrt(2pi)) * sum_k (-1)^k (t/2)^k / (k!(2k+1))   [erf Taylor]
// 17 terms: truncation err in gelu < 1e-4 on |s|<=3; clamp tail err
// <= |s|*(1-Phi(3)) ~ 7e-3 worst case at |s|~5 (threshold is 7.25e-2).
#define NC 17
struct GeluCoef {
    float c[NC];
    constexpr GeluCoef() : c{} {
        double fact = 1.0;   // k!
        double p5   = 1.0;   // 0.5^k
        for (int k = 0; k < NC; ++k) {
            if (k > 0) { fact *= (double)k; p5 *= 0.5; }
            double ck = ((k & 1) ? -1.0 : 1.0) * p5 / (fact * (double)(2 * k + 1));
            c[k] = (float)(0.3989422804014327 * ck);   // 1/sqrt(2*pi) prefactor
        }
    }
};
static constexpr GeluCoef GC{};

__device__ __forceinline__ float gelu_poly(float s) {
    float c = __builtin_amdgcn_fmed3f(s, -3.0f, 3.0f);
    float t = c * c;
    float q = GC.c[NC - 1];
    #pragma unroll
    for (int k = NC - 2; k >= 0; --k) q = __builtin_fmaf(q, t, GC.c[k]);
    return s * __builtin_fmaf(c, q, 0.5f);
}

// Kernel 1: per-row projection, 4 rows per block (2 per 128-thread group).
#define PR 4
__global__ __launch_bounds__(256) void proj_kernel(
    const float* __restrict__ x0, const float* __restrict__ x,
    const float* __restrict__ y,  const float* __restrict__ W1,
    const float* __restrict__ b1, float* __restrict__ hx, float* __restrict__ hy) {
    const int e = threadIdx.x & (DD - 1);
    const int g = threadIdx.x >> 7;          // 0/1: which row pair
    const int nxb = (BB * NN1) / PR;         // 256 blocks for hx
    const float* Wa = W1;
    const float* Wb = W1 + DD * DD;
    const float* Wc = W1 + 2 * DD * DD;

    if (blockIdx.x < nxb) {
        const int row0 = blockIdx.x * PR + g * 2;
        float acc0 = b1[e], acc1 = b1[e];
        #pragma unroll 8
        for (int d = 0; d < DD; ++d) {
            const float wa = Wa[d * DD + e];
            const float wb = Wb[d * DD + e];
            acc0 += x0[(row0 + 0) * DD + d] * wa + x[(row0 + 0) * DD + d] * wb;
            acc1 += x0[(row0 + 1) * DD + d] * wa + x[(row0 + 1) * DD + d] * wb;
        }
        hx[(row0 + 0) * DD + e] = acc0;
        hx[(row0 + 1) * DD + e] = acc1;
    } else {
        const int row0 = (blockIdx.x - nxb) * PR + g * 2;
        float acc0 = 0.f, acc1 = 0.f;
        #pragma unroll 8
        for (int d = 0; d < DD; ++d) {
            const float wc = Wc[d * DD + e];
            acc0 += y[(row0 + 0) * DD + d] * wc;
            acc1 += y[(row0 + 1) * DD + d] * wc;
        }
        hy[(row0 + 0) * DD + e] = acc0;
        hy[(row0 + 1) * DD + e] = acc1;
    }
}

// Kernel 2: 32x32 (n,m) tile per block, 2x2 outputs per thread.
__global__ __launch_bounds__(256) void cross_kernel(
    const float* __restrict__ hx, const float* __restrict__ hy,
    const float* __restrict__ W2, const float* __restrict__ b2,
    float* __restrict__ out) {
    __shared__ float sx[TS][SXPAD];
    __shared__ float sy[TS][SXPAD];
    __shared__ float sw[DD];

    const int b  = blockIdx.z;
    const int n0 = blockIdx.y * TS;
    const int m0 = blockIdx.x * TS;
    const int tid = threadIdx.x;

    for (int i = tid; i < TS * (DD / 4); i += 256) {
        const int r  = i >> 5;
        const int c4 = i & 31;
        *(float4*)&sx[r][c4 * 4] =
            *(const float4*)&hx[((b * NN1) + n0 + r) * DD + c4 * 4];
        *(float4*)&sy[r][c4 * 4] =
            *(const float4*)&hy[((b * NN2) + m0 + r) * DD + c4 * 4];
    }
    if (tid < DD) sw[tid] = W2[tid];
    __syncthreads();

    const int tn = (tid >> 4) * 2;
    const int tm = (tid & 15) * 2;

    float acc00 = 0.f, acc01 = 0.f, acc10 = 0.f, acc11 = 0.f;

    #pragma unroll 4
    for (int e4 = 0; e4 < DD / 4; ++e4) {
        const float4 a0 = *(const float4*)&sx[tn][e4 * 4];
        const float4 a1 = *(const float4*)&sx[tn + 1][e4 * 4];
        const float4 c0 = *(const float4*)&sy[tm][e4 * 4];
        const float4 c1 = *(const float4*)&sy[tm + 1][e4 * 4];
        const float4 w  = *(const float4*)&sw[e4 * 4];

        acc00 += gelu_poly(a0.x + c0.x) * w.x;
        acc01 += gelu_poly(a0.x + c1.x) * w.x;
        acc10 += gelu_poly(a1.x + c0.x) * w.x;
        acc11 += gelu_poly(a1.x + c1.x) * w.x;

        acc00 += gelu_poly(a0.y + c0.y) * w.y;
        acc01 += gelu_poly(a0.y + c1.y) * w.y;
        acc10 += gelu_poly(a1.y + c0.y) * w.y;
        acc11 += gelu_poly(a1.y + c1.y) * w.y;

        acc00 += gelu_poly(a0.z + c0.z) * w.z;
        acc01 += gelu_poly(a0.z + c1.z) * w.z;
        acc10 += gelu_poly(a1.z + c0.z) * w.z;
        acc11 += gelu_poly(a1.z + c1.z) * w.z;

        acc00 += gelu_poly(a0.w + c0.w) * w.w;
        acc01 += gelu_poly(a0.w + c1.w) * w.w;
        acc10 += gelu_poly(a1.w + c0.w) * w.w;
        acc11 += gelu_poly(a1.w + c1.w) * w.w;
    }

    const float bias = b2[0];
    float* o0 = &out[((size_t)(b * NN1) + n0 + tn) * NN2 + m0 + tm];
    float* o1 = o0 + NN2;
    *(float2*)o0 = make_float2(acc00 + bias, acc01 + bias);
    *(float2*)o1 = make_float2(acc10 + bias, acc11 + bias);
}

extern "C" void kernel_launch(void* const* d_in, const int* in_sizes, int n_in,
                              void* d_out, int out_size, void* d_ws, size_t ws_size,
                              hipStream_t stream) {
    const float* x0 = (const float*)d_in[0];
    const float* x  = (const float*)d_in[1];
    const float* y  = (const float*)d_in[2];
    const float* W1 = (const float*)d_in[3];
    const float* b1 = (const float*)d_in[4];
    const float* W2 = (const float*)d_in[5];
    const float* b2 = (const float*)d_in[6];
    float* out = (float*)d_out;

    float* hx = (float*)d_ws;
    float* hy = hx + (size_t)BB * NN1 * DD;

    const int nblocks = (BB * NN1) / PR + (BB * NN2) / PR;  // 512
    proj_kernel<<<nblocks, 256, 0, stream>>>(x0, x, y, W1, b1, hx, hy);
    cross_kernel<<<dim3(NN2 / TS, NN1 / TS, BB), 256, 0, stream>>>(hx, hy, W2, b2, out);
}

// Round 5
// 43.043 us; speedup vs baseline: 1.0456x; 1.0456x over previous
//
#include <hip/hip_runtime.h>

#define BB 2
#define NN1 512
#define NN2 512
#define DD 128
#define TS 32          // cross tile: 32x32 (n,m) per block
#define SXPAD 132      // row stride in floats: 16B-aligned, rows shift banks

// ---- Trans-free GELU via degree-9 Chebyshev fit -------------------------
// gelu(s) = s*Phi(s), Phi(s) = 0.5 + c*P(c^2), c = clamp(s,-3,3)
// P(t) = 0.5*erf(sqrt(t)/sqrt(2))/sqrt(t), entire in t, fitted on [0,9]
// by Chebyshev interpolation (N=10 nodes), evaluated as monomial Horner in
// u = t/4.5 - 1 in [-1,1]. Interp error ~1e-5; clamp tail err <= |s|*1.35e-3.
struct GeluPoly {
    float p[10];
    constexpr GeluPoly() : p{} {
        const int N = 10;
        const double PI = 3.14159265358979323846;
        double fv[10] = {};
        double xv[10] = {};
        for (int j = 0; j < N; ++j) {
            double th = PI * (j + 0.5) / N;
            // cos(th), th in (0,pi): Taylor
            double cth = 1.0, term = 1.0, t2 = th * th;
            for (int k = 1; k <= 30; ++k) {
                term *= -t2 / ((2.0 * k - 1.0) * (2.0 * k));
                cth += term;
            }
            xv[j] = cth;
            double t = 4.5 * (cth + 1.0);          // node in [0,9]
            // sqrt(t): Newton
            double s = t > 1.0 ? t : 1.0;
            for (int it = 0; it < 64; ++it) s = 0.5 * (s + t / s);
            // erf(x), x = s/sqrt(2) <= 2.122: Taylor
            double x = s * 0.70710678118654752440;
            double esum = 0.0, pw = x, fact = 1.0;
            for (int k = 0; k < 48; ++k) {
                if (k > 0) { fact *= (double)k; pw *= x * x; }
                double tk = pw / (fact * (2.0 * k + 1.0));
                esum += (k & 1) ? -tk : tk;
            }
            double erfv = 1.12837916709551257390 * esum;  // 2/sqrt(pi)
            fv[j] = 0.5 * erfv / s;                        // P(t_j)
        }
        // Chebyshev coefficients
        double ck[10] = {};
        for (int k = 0; k < N; ++k) {
            double sum = 0.0;
            for (int j = 0; j < N; ++j) {
                double Tk = 1.0;
                if (k >= 1) {
                    double Tm2 = 1.0, Tm1 = xv[j];
                    Tk = xv[j];
                    for (int i = 2; i <= k; ++i) {
                        Tk = 2.0 * xv[j] * Tm1 - Tm2;
                        Tm2 = Tm1; Tm1 = Tk;
                    }
                }
                sum += fv[j] * Tk;
            }
            ck[k] = 2.0 * sum / N;
        }
        ck[0] *= 0.5;
        // Chebyshev -> monomial (in u)
        double T[10][10] = {};
        T[0][0] = 1.0;
        T[1][1] = 1.0;
        for (int k = 2; k < N; ++k)
            for (int i = 0; i < N; ++i)
                T[k][i] = 2.0 * (i > 0 ? T[k - 1][i - 1] : 0.0) - T[k - 2][i];
        double pd[10] = {};
        for (int k = 0; k < N; ++k)
            for (int i = 0; i < N; ++i)
                pd[i] += ck[k] * T[k][i];
        for (int i = 0; i < N; ++i) p[i] = (float)pd[i];
    }
};
static constexpr GeluPoly GP{};

__device__ __forceinline__ float gelu_poly(float s) {
    float c = __builtin_amdgcn_fmed3f(s, -3.0f, 3.0f);
    float t = c * c;
    float u = __builtin_fmaf(t, 0.22222222222222222f, -1.0f);
    float q = GP.p[9];
    #pragma unroll
    for (int k = 8; k >= 0; --k) q = __builtin_fmaf(q, u, GP.p[k]);
    float phi = __builtin_fmaf(c, q, 0.5f);
    return s * phi;
}

// Kernel 1: per-row projection, 8 rows per block, 256 threads.
#define PR 8
__global__ __launch_bounds__(256) void proj_kernel(
    const float* __restrict__ x0, const float* __restrict__ x,
    const float* __restrict__ y,  const float* __restrict__ W1,
    const float* __restrict__ b1, float* __restrict__ hx, float* __restrict__ hy) {
    const int e = threadIdx.x & (DD - 1);
    const int g = threadIdx.x >> 7;
    const int nxb = (BB * NN1) / PR;
    const float* Wa = W1;
    const float* Wb = W1 + DD * DD;
    const float* Wc = W1 + 2 * DD * DD;

    if (blockIdx.x < nxb) {
        const int row0 = blockIdx.x * PR + g * (PR / 2);
        float acc0 = b1[e], acc1 = b1[e], acc2 = b1[e], acc3 = b1[e];
        #pragma unroll 4
        for (int d = 0; d < DD; ++d) {
            const float wa = Wa[d * DD + e];
            const float wb = Wb[d * DD + e];
            acc0 += x0[(row0 + 0) * DD + d] * wa + x[(row0 + 0) * DD + d] * wb;
            acc1 += x0[(row0 + 1) * DD + d] * wa + x[(row0 + 1) * DD + d] * wb;
            acc2 += x0[(row0 + 2) * DD + d] * wa + x[(row0 + 2) * DD + d] * wb;
            acc3 += x0[(row0 + 3) * DD + d] * wa + x[(row0 + 3) * DD + d] * wb;
        }
        hx[(row0 + 0) * DD + e] = acc0;
        hx[(row0 + 1) * DD + e] = acc1;
        hx[(row0 + 2) * DD + e] = acc2;
        hx[(row0 + 3) * DD + e] = acc3;
    } else {
        const int row0 = (blockIdx.x - nxb) * PR + g * (PR / 2);
        float acc0 = 0.f, acc1 = 0.f, acc2 = 0.f, acc3 = 0.f;
        #pragma unroll 4
        for (int d = 0; d < DD; ++d) {
            const float wc = Wc[d * DD + e];
            acc0 += y[(row0 + 0) * DD + d] * wc;
            acc1 += y[(row0 + 1) * DD + d] * wc;
            acc2 += y[(row0 + 2) * DD + d] * wc;
            acc3 += y[(row0 + 3) * DD + d] * wc;
        }
        hy[(row0 + 0) * DD + e] = acc0;
        hy[(row0 + 1) * DD + e] = acc1;
        hy[(row0 + 2) * DD + e] = acc2;
        hy[(row0 + 3) * DD + e] = acc3;
    }
}

// Kernel 2: 32x32 (n,m) tile per block, 2x2 outputs per thread.
__global__ __launch_bounds__(256) void cross_kernel(
    const float* __restrict__ hx, const float* __restrict__ hy,
    const float* __restrict__ W2, const float* __restrict__ b2,
    float* __restrict__ out) {
    __shared__ float sx[TS][SXPAD];
    __shared__ float sy[TS][SXPAD];
    __shared__ float sw[DD];

    const int b  = blockIdx.z;
    const int n0 = blockIdx.y * TS;
    const int m0 = blockIdx.x * TS;
    const int tid = threadIdx.x;

    for (int i = tid; i < TS * (DD / 4); i += 256) {
        const int r  = i >> 5;
        const int c4 = i & 31;
        *(float4*)&sx[r][c4 * 4] =
            *(const float4*)&hx[((b * NN1) + n0 + r) * DD + c4 * 4];
        *(float4*)&sy[r][c4 * 4] =
            *(const float4*)&hy[((b * NN2) + m0 + r) * DD + c4 * 4];
    }
    if (tid < DD) sw[tid] = W2[tid];
    __syncthreads();

    const int tn = (tid >> 4) * 2;
    const int tm = (tid & 15) * 2;

    float acc00 = 0.f, acc01 = 0.f, acc10 = 0.f, acc11 = 0.f;

    #pragma unroll 4
    for (int e4 = 0; e4 < DD / 4; ++e4) {
        const float4 a0 = *(const float4*)&sx[tn][e4 * 4];
        const float4 a1 = *(const float4*)&sx[tn + 1][e4 * 4];
        const float4 c0 = *(const float4*)&sy[tm][e4 * 4];
        const float4 c1 = *(const float4*)&sy[tm + 1][e4 * 4];
        const float4 w  = *(const float4*)&sw[e4 * 4];

        acc00 = __builtin_fmaf(gelu_poly(a0.x + c0.x), w.x, acc00);
        acc01 = __builtin_fmaf(gelu_poly(a0.x + c1.x), w.x, acc01);
        acc10 = __builtin_fmaf(gelu_poly(a1.x + c0.x), w.x, acc10);
        acc11 = __builtin_fmaf(gelu_poly(a1.x + c1.x), w.x, acc11);

        acc00 = __builtin_fmaf(gelu_poly(a0.y + c0.y), w.y, acc00);
        acc01 = __builtin_fmaf(gelu_poly(a0.y + c1.y), w.y, acc01);
        acc10 = __builtin_fmaf(gelu_poly(a1.y + c0.y), w.y, acc10);
        acc11 = __builtin_fmaf(gelu_poly(a1.y + c1.y), w.y, acc11);

        acc00 = __builtin_fmaf(gelu_poly(a0.z + c0.z), w.z, acc00);
        acc01 = __builtin_fmaf(gelu_poly(a0.z + c1.z), w.z, acc01);
        acc10 = __builtin_fmaf(gelu_poly(a1.z + c0.z), w.z, acc10);
        acc11 = __builtin_fmaf(gelu_poly(a1.z + c1.z), w.z, acc11);

        acc00 = __builtin_fmaf(gelu_poly(a0.w + c0.w), w.w, acc00);
        acc01 = __builtin_fmaf(gelu_poly(a0.w + c1.w), w.w, acc01);
        acc10 = __builtin_fmaf(gelu_poly(a1.w + c0.w), w.w, acc10);
        acc11 = __builtin_fmaf(gelu_poly(a1.w + c1.w), w.w, acc11);
    }

    const float bias = b2[0];
    float* o0 = &out[((size_t)(b * NN1) + n0 + tn) * NN2 + m0 + tm];
    float* o1 = o0 + NN2;
    *(float2*)o0 = make_float2(acc00 + bias, acc01 + bias);
    *(float2*)o1 = make_float2(acc10 + bias, acc11 + bias);
}

extern "C" void kernel_launch(void* const* d_in, const int* in_sizes, int n_in,
                              void* d_out, int out_size, void* d_ws, size_t ws_size,
                              hipStream_t stream) {
    const float* x0 = (const float*)d_in[0];
    const float* x  = (const float*)d_in[1];
    const float* y  = (const float*)d_in[2];
    const float* W1 = (const float*)d_in[3];
    const float* b1 = (const float*)d_in[4];
    const float* W2 = (const float*)d_in[5];
    const float* b2 = (const float*)d_in[6];
    float* out = (float*)d_out;

    float* hx = (float*)d_ws;
    float* hy = hx + (size_t)BB * NN1 * DD;

    const int nblocks = (BB * NN1) / PR + (BB * NN2) / PR;  // 256
    proj_kernel<<<nblocks, 256, 0, stream>>>(x0, x, y, W1, b1, hx, hy);
    cross_kernel<<<dim3(NN2 / TS, NN1 / TS, BB), 256, 0, stream>>>(hx, hy, W2, b2, out);
}

// Round 6
// 41.915 us; speedup vs baseline: 1.0737x; 1.0269x over previous
//
#include <hip/hip_runtime.h>

#define BB 2
#define NN1 512
#define NN2 512
#define DD 128
#define TS 32          // cross tile: 32x32 (n,m) per block
#define SXPAD 132      // row stride in floats: 528B = 33*16B (b128-aligned), rows shift banks

typedef float v2f __attribute__((ext_vector_type(2)));
typedef float v4f __attribute__((ext_vector_type(4)));

// ---- Trans-free GELU via degree-9 Chebyshev fit (verified R5: absmax 0.0156)
struct GeluPoly {
    float p[10];
    constexpr GeluPoly() : p{} {
        const int N = 10;
        const double PI = 3.14159265358979323846;
        double fv[10] = {};
        double xv[10] = {};
        for (int j = 0; j < N; ++j) {
            double th = PI * (j + 0.5) / N;
            double cth = 1.0, term = 1.0, t2 = th * th;
            for (int k = 1; k <= 30; ++k) {
                term *= -t2 / ((2.0 * k - 1.0) * (2.0 * k));
                cth += term;
            }
            xv[j] = cth;
            double t = 4.5 * (cth + 1.0);
            double s = t > 1.0 ? t : 1.0;
            for (int it = 0; it < 64; ++it) s = 0.5 * (s + t / s);
            double x = s * 0.70710678118654752440;
            double esum = 0.0, pw = x, fact = 1.0;
            for (int k = 0; k < 48; ++k) {
                if (k > 0) { fact *= (double)k; pw *= x * x; }
                double tk = pw / (fact * (2.0 * k + 1.0));
                esum += (k & 1) ? -tk : tk;
            }
            double erfv = 1.12837916709551257390 * esum;
            fv[j] = 0.5 * erfv / s;
        }
        double ck[10] = {};
        for (int k = 0; k < N; ++k) {
            double sum = 0.0;
            for (int j = 0; j < N; ++j) {
                double Tk = 1.0;
                if (k >= 1) {
                    double Tm2 = 1.0, Tm1 = xv[j];
                    Tk = xv[j];
                    for (int i = 2; i <= k; ++i) {
                        Tk = 2.0 * xv[j] * Tm1 - Tm2;
                        Tm2 = Tm1; Tm1 = Tk;
                    }
                }
                sum += fv[j] * Tk;
            }
            ck[k] = 2.0 * sum / N;
        }
        ck[0] *= 0.5;
        double T[10][10] = {};
        T[0][0] = 1.0;
        T[1][1] = 1.0;
        for (int k = 2; k < N; ++k)
            for (int i = 0; i < N; ++i)
                T[k][i] = 2.0 * (i > 0 ? T[k - 1][i - 1] : 0.0) - T[k - 2][i];
        double pd[10] = {};
        for (int k = 0; k < N; ++k)
            for (int i = 0; i < N; ++i)
                pd[i] += ck[k] * T[k][i];
        for (int i = 0; i < N; ++i) p[i] = (float)pd[i];
    }
};
static constexpr GeluPoly GP{};

// Packed (2-wide) gelu: lowers to v_pk_* f32 ops.
__device__ __forceinline__ v2f gelu2(v2f s) {
    v2f c = __builtin_elementwise_max(s, v2f{-3.0f, -3.0f});
    c = __builtin_elementwise_min(c, v2f{3.0f, 3.0f});
    v2f t = c * c;
    v2f u = __builtin_elementwise_fma(t, v2f{0.22222222222222222f, 0.22222222222222222f},
                                      v2f{-1.0f, -1.0f});
    v2f q = v2f{GP.p[9], GP.p[9]};
    #pragma unroll
    for (int k = 8; k >= 0; --k)
        q = __builtin_elementwise_fma(q, u, v2f{GP.p[k], GP.p[k]});
    v2f phi = __builtin_elementwise_fma(c, q, v2f{0.5f, 0.5f});
    return s * phi;
}

// Kernel 1: per-row projection, 8 rows per block, 256 threads. (unchanged)
#define PR 8
__global__ __launch_bounds__(256) void proj_kernel(
    const float* __restrict__ x0, const float* __restrict__ x,
    const float* __restrict__ y,  const float* __restrict__ W1,
    const float* __restrict__ b1, float* __restrict__ hx, float* __restrict__ hy) {
    const int e = threadIdx.x & (DD - 1);
    const int g = threadIdx.x >> 7;
    const int nxb = (BB * NN1) / PR;
    const float* Wa = W1;
    const float* Wb = W1 + DD * DD;
    const float* Wc = W1 + 2 * DD * DD;

    if (blockIdx.x < nxb) {
        const int row0 = blockIdx.x * PR + g * (PR / 2);
        float acc0 = b1[e], acc1 = b1[e], acc2 = b1[e], acc3 = b1[e];
        #pragma unroll 4
        for (int d = 0; d < DD; ++d) {
            const float wa = Wa[d * DD + e];
            const float wb = Wb[d * DD + e];
            acc0 += x0[(row0 + 0) * DD + d] * wa + x[(row0 + 0) * DD + d] * wb;
            acc1 += x0[(row0 + 1) * DD + d] * wa + x[(row0 + 1) * DD + d] * wb;
            acc2 += x0[(row0 + 2) * DD + d] * wa + x[(row0 + 2) * DD + d] * wb;
            acc3 += x0[(row0 + 3) * DD + d] * wa + x[(row0 + 3) * DD + d] * wb;
        }
        hx[(row0 + 0) * DD + e] = acc0;
        hx[(row0 + 1) * DD + e] = acc1;
        hx[(row0 + 2) * DD + e] = acc2;
        hx[(row0 + 3) * DD + e] = acc3;
    } else {
        const int row0 = (blockIdx.x - nxb) * PR + g * (PR / 2);
        float acc0 = 0.f, acc1 = 0.f, acc2 = 0.f, acc3 = 0.f;
        #pragma unroll 4
        for (int d = 0; d < DD; ++d) {
            const float wc = Wc[d * DD + e];
            acc0 += y[(row0 + 0) * DD + d] * wc;
            acc1 += y[(row0 + 1) * DD + d] * wc;
            acc2 += y[(row0 + 2) * DD + d] * wc;
            acc3 += y[(row0 + 3) * DD + d] * wc;
        }
        hy[(row0 + 0) * DD + e] = acc0;
        hy[(row0 + 1) * DD + e] = acc1;
        hy[(row0 + 2) * DD + e] = acc2;
        hy[(row0 + 3) * DD + e] = acc3;
    }
}

// Kernel 2: 32x32 (n,m) tile, 2x2 outputs/thread as (i, i+16) pairs (bank-conflict-free),
// packed-f32 gelu.
__global__ __launch_bounds__(256) void cross_kernel(
    const float* __restrict__ hx, const float* __restrict__ hy,
    const float* __restrict__ W2, const float* __restrict__ b2,
    float* __restrict__ out) {
    __shared__ float sx[TS][SXPAD];
    __shared__ float sy[TS][SXPAD];
    __shared__ float sw[DD];

    const int b  = blockIdx.z;
    const int n0 = blockIdx.y * TS;
    const int m0 = blockIdx.x * TS;
    const int tid = threadIdx.x;

    for (int i = tid; i < TS * (DD / 4); i += 256) {
        const int r  = i >> 5;
        const int c4 = i & 31;
        *(v4f*)&sx[r][c4 * 4] =
            *(const v4f*)&hx[((b * NN1) + n0 + r) * DD + c4 * 4];
        *(v4f*)&sy[r][c4 * 4] =
            *(const v4f*)&hy[((b * NN2) + m0 + r) * DD + c4 * 4];
    }
    if (tid < DD) sw[tid] = W2[tid];
    __syncthreads();

    const int q = tid >> 4;      // rows q, q+16
    const int p = tid & 15;      // cols p, p+16

    v2f acc00 = {0.f, 0.f}, acc01 = {0.f, 0.f};
    v2f acc10 = {0.f, 0.f}, acc11 = {0.f, 0.f};

    #pragma unroll 4
    for (int e4 = 0; e4 < DD / 4; ++e4) {
        const v4f a0 = *(const v4f*)&sx[q][e4 * 4];
        const v4f a1 = *(const v4f*)&sx[q + 16][e4 * 4];
        const v4f c0 = *(const v4f*)&sy[p][e4 * 4];
        const v4f c1 = *(const v4f*)&sy[p + 16][e4 * 4];
        const v4f w  = *(const v4f*)&sw[e4 * 4];

        const v2f a0l = {a0.x, a0.y}, a0h = {a0.z, a0.w};
        const v2f a1l = {a1.x, a1.y}, a1h = {a1.z, a1.w};
        const v2f c0l = {c0.x, c0.y}, c0h = {c0.z, c0.w};
        const v2f c1l = {c1.x, c1.y}, c1h = {c1.z, c1.w};
        const v2f wl  = {w.x, w.y},   wh  = {w.z, w.w};

        acc00 = __builtin_elementwise_fma(gelu2(a0l + c0l), wl, acc00);
        acc01 = __builtin_elementwise_fma(gelu2(a0l + c1l), wl, acc01);
        acc10 = __builtin_elementwise_fma(gelu2(a1l + c0l), wl, acc10);
        acc11 = __builtin_elementwise_fma(gelu2(a1l + c1l), wl, acc11);

        acc00 = __builtin_elementwise_fma(gelu2(a0h + c0h), wh, acc00);
        acc01 = __builtin_elementwise_fma(gelu2(a0h + c1h), wh, acc01);
        acc10 = __builtin_elementwise_fma(gelu2(a1h + c0h), wh, acc10);
        acc11 = __builtin_elementwise_fma(gelu2(a1h + c1h), wh, acc11);
    }

    const float bias = b2[0];
    float* orow0 = &out[((size_t)(b * NN1) + n0 + q) * NN2 + m0];
    float* orow1 = orow0 + (size_t)16 * NN2;
    orow0[p]      = acc00.x + acc00.y + bias;
    orow0[p + 16] = acc01.x + acc01.y + bias;
    orow1[p]      = acc10.x + acc10.y + bias;
    orow1[p + 16] = acc11.x + acc11.y + bias;
}

extern "C" void kernel_launch(void* const* d_in, const int* in_sizes, int n_in,
                              void* d_out, int out_size, void* d_ws, size_t ws_size,
                              hipStream_t stream) {
    const float* x0 = (const float*)d_in[0];
    const float* x  = (const float*)d_in[1];
    const float* y  = (const float*)d_in[2];
    const float* W1 = (const float*)d_in[3];
    const float* b1 = (const float*)d_in[4];
    const float* W2 = (const float*)d_in[5];
    const float* b2 = (const float*)d_in[6];
    float* out = (float*)d_out;

    float* hx = (float*)d_ws;
    float* hy = hx + (size_t)BB * NN1 * DD;

    const int nblocks = (BB * NN1) / PR + (BB * NN2) / PR;  // 256
    proj_kernel<<<nblocks, 256, 0, stream>>>(x0, x, y, W1, b1, hx, hy);
    cross_kernel<<<dim3(NN2 / TS, NN1 / TS, BB), 256, 0, stream>>>(hx, hy, W2, b2, out);
}

// Round 7
// 41.784 us; speedup vs baseline: 1.0770x; 1.0031x over previous
//
#include <hip/hip_runtime.h>

#define BB 2
#define NN1 512
#define NN2 512
#define DD 128
#define TS 32          // cross tile: 32x32 (n,m) per block
#define SXPAD 132      // row stride in floats: 528B = 33*16B (b128-aligned), rows shift banks

typedef float v2f __attribute__((ext_vector_type(2)));
typedef float v4f __attribute__((ext_vector_type(4)));

// ---- Trans-free GELU via degree-9 Chebyshev fit (verified R5/R6: absmax 0.0156)
struct GeluPoly {
    float p[10];
    constexpr GeluPoly() : p{} {
        const int N = 10;
        const double PI = 3.14159265358979323846;
        double fv[10] = {};
        double xv[10] = {};
        for (int j = 0; j < N; ++j) {
            double th = PI * (j + 0.5) / N;
            double cth = 1.0, term = 1.0, t2 = th * th;
            for (int k = 1; k <= 30; ++k) {
                term *= -t2 / ((2.0 * k - 1.0) * (2.0 * k));
                cth += term;
            }
            xv[j] = cth;
            double t = 4.5 * (cth + 1.0);
            double s = t > 1.0 ? t : 1.0;
            for (int it = 0; it < 64; ++it) s = 0.5 * (s + t / s);
            double x = s * 0.70710678118654752440;
            double esum = 0.0, pw = x, fact = 1.0;
            for (int k = 0; k < 48; ++k) {
                if (k > 0) { fact *= (double)k; pw *= x * x; }
                double tk = pw / (fact * (2.0 * k + 1.0));
                esum += (k & 1) ? -tk : tk;
            }
            double erfv = 1.12837916709551257390 * esum;
            fv[j] = 0.5 * erfv / s;
        }
        double ck[10] = {};
        for (int k = 0; k < N; ++k) {
            double sum = 0.0;
            for (int j = 0; j < N; ++j) {
                double Tk = 1.0;
                if (k >= 1) {
                    double Tm2 = 1.0, Tm1 = xv[j];
                    Tk = xv[j];
                    for (int i = 2; i <= k; ++i) {
                        Tk = 2.0 * xv[j] * Tm1 - Tm2;
                        Tm2 = Tm1; Tm1 = Tk;
                    }
                }
                sum += fv[j] * Tk;
            }
            ck[k] = 2.0 * sum / N;
        }
        ck[0] *= 0.5;
        double T[10][10] = {};
        T[0][0] = 1.0;
        T[1][1] = 1.0;
        for (int k = 2; k < N; ++k)
            for (int i = 0; i < N; ++i)
                T[k][i] = 2.0 * (i > 0 ? T[k - 1][i - 1] : 0.0) - T[k - 2][i];
        double pd[10] = {};
        for (int k = 0; k < N; ++k)
            for (int i = 0; i < N; ++i)
                pd[i] += ck[k] * T[k][i];
        for (int i = 0; i < N; ++i) p[i] = (float)pd[i];
    }
};
static constexpr GeluPoly GP{};

// Packed (2-wide) gelu: lowers to v_pk_* f32 ops.
__device__ __forceinline__ v2f gelu2(v2f s) {
    v2f c = __builtin_elementwise_max(s, v2f{-3.0f, -3.0f});
    c = __builtin_elementwise_min(c, v2f{3.0f, 3.0f});
    v2f t = c * c;
    v2f u = __builtin_elementwise_fma(t, v2f{0.22222222222222222f, 0.22222222222222222f},
                                      v2f{-1.0f, -1.0f});
    v2f q = v2f{GP.p[9], GP.p[9]};
    #pragma unroll
    for (int k = 8; k >= 0; --k)
        q = __builtin_elementwise_fma(q, u, v2f{GP.p[k], GP.p[k]});
    v2f phi = __builtin_elementwise_fma(c, q, v2f{0.5f, 0.5f});
    return s * phi;
}

// Kernel 1: per-row projection, 8 rows per block, 256 threads. (unchanged from R6)
#define PR 8
__global__ __launch_bounds__(256) void proj_kernel(
    const float* __restrict__ x0, const float* __restrict__ x,
    const float* __restrict__ y,  const float* __restrict__ W1,
    const float* __restrict__ b1, float* __restrict__ hx, float* __restrict__ hy) {
    const int e = threadIdx.x & (DD - 1);
    const int g = threadIdx.x >> 7;
    const int nxb = (BB * NN1) / PR;
    const float* Wa = W1;
    const float* Wb = W1 + DD * DD;
    const float* Wc = W1 + 2 * DD * DD;

    if (blockIdx.x < nxb) {
        const int row0 = blockIdx.x * PR + g * (PR / 2);
        float acc0 = b1[e], acc1 = b1[e], acc2 = b1[e], acc3 = b1[e];
        #pragma unroll 4
        for (int d = 0; d < DD; ++d) {
            const float wa = Wa[d * DD + e];
            const float wb = Wb[d * DD + e];
            acc0 += x0[(row0 + 0) * DD + d] * wa + x[(row0 + 0) * DD + d] * wb;
            acc1 += x0[(row0 + 1) * DD + d] * wa + x[(row0 + 1) * DD + d] * wb;
            acc2 += x0[(row0 + 2) * DD + d] * wa + x[(row0 + 2) * DD + d] * wb;
            acc3 += x0[(row0 + 3) * DD + d] * wa + x[(row0 + 3) * DD + d] * wb;
        }
        hx[(row0 + 0) * DD + e] = acc0;
        hx[(row0 + 1) * DD + e] = acc1;
        hx[(row0 + 2) * DD + e] = acc2;
        hx[(row0 + 3) * DD + e] = acc3;
    } else {
        const int row0 = (blockIdx.x - nxb) * PR + g * (PR / 2);
        float acc0 = 0.f, acc1 = 0.f, acc2 = 0.f, acc3 = 0.f;
        #pragma unroll 4
        for (int d = 0; d < DD; ++d) {
            const float wc = Wc[d * DD + e];
            acc0 += y[(row0 + 0) * DD + d] * wc;
            acc1 += y[(row0 + 1) * DD + d] * wc;
            acc2 += y[(row0 + 2) * DD + d] * wc;
            acc3 += y[(row0 + 3) * DD + d] * wc;
        }
        hy[(row0 + 0) * DD + e] = acc0;
        hy[(row0 + 1) * DD + e] = acc1;
        hy[(row0 + 2) * DD + e] = acc2;
        hy[(row0 + 3) * DD + e] = acc3;
    }
}

// Kernel 2: identical to R6 except __launch_bounds__(256, 2):
// grid supplies only 2 blocks/CU, so give the register allocator the full
// 2-waves/SIMD budget (~256 VGPR) instead of the default high-occupancy target
// (R6 chose 72 VGPR -> serialized LDS loads, 80% stall).
__global__ __launch_bounds__(256, 2) void cross_kernel(
    const float* __restrict__ hx, const float* __restrict__ hy,
    const float* __restrict__ W2, const float* __restrict__ b2,
    float* __restrict__ out) {
    __shared__ float sx[TS][SXPAD];
    __shared__ float sy[TS][SXPAD];
    __shared__ float sw[DD];

    const int b  = blockIdx.z;
    const int n0 = blockIdx.y * TS;
    const int m0 = blockIdx.x * TS;
    const int tid = threadIdx.x;

    for (int i = tid; i < TS * (DD / 4); i += 256) {
        const int r  = i >> 5;
        const int c4 = i & 31;
        *(v4f*)&sx[r][c4 * 4] =
            *(const v4f*)&hx[((b * NN1) + n0 + r) * DD + c4 * 4];
        *(v4f*)&sy[r][c4 * 4] =
            *(const v4f*)&hy[((b * NN2) + m0 + r) * DD + c4 * 4];
    }
    if (tid < DD) sw[tid] = W2[tid];
    __syncthreads();

    const int q = tid >> 4;      // rows q, q+16
    const int p = tid & 15;      // cols p, p+16

    v2f acc00 = {0.f, 0.f}, acc01 = {0.f, 0.f};
    v2f acc10 = {0.f, 0.f}, acc11 = {0.f, 0.f};

    #pragma unroll 4
    for (int e4 = 0; e4 < DD / 4; ++e4) {
        const v4f a0 = *(const v4f*)&sx[q][e4 * 4];
        const v4f a1 = *(const v4f*)&sx[q + 16][e4 * 4];
        const v4f c0 = *(const v4f*)&sy[p][e4 * 4];
        const v4f c1 = *(const v4f*)&sy[p + 16][e4 * 4];
        const v4f w  = *(const v4f*)&sw[e4 * 4];

        const v2f a0l = {a0.x, a0.y}, a0h = {a0.z, a0.w};
        const v2f a1l = {a1.x, a1.y}, a1h = {a1.z, a1.w};
        const v2f c0l = {c0.x, c0.y}, c0h = {c0.z, c0.w};
        const v2f c1l = {c1.x, c1.y}, c1h = {c1.z, c1.w};
        const v2f wl  = {w.x, w.y},   wh  = {w.z, w.w};

        acc00 = __builtin_elementwise_fma(gelu2(a0l + c0l), wl, acc00);
        acc01 = __builtin_elementwise_fma(gelu2(a0l + c1l), wl, acc01);
        acc10 = __builtin_elementwise_fma(gelu2(a1l + c0l), wl, acc10);
        acc11 = __builtin_elementwise_fma(gelu2(a1l + c1l), wl, acc11);

        acc00 = __builtin_elementwise_fma(gelu2(a0h + c0h), wh, acc00);
        acc01 = __builtin_elementwise_fma(gelu2(a0h + c1h), wh, acc01);
        acc10 = __builtin_elementwise_fma(gelu2(a1h + c0h), wh, acc10);
        acc11 = __builtin_elementwise_fma(gelu2(a1h + c1h), wh, acc11);
    }

    const float bias = b2[0];
    float* orow0 = &out[((size_t)(b * NN1) + n0 + q) * NN2 + m0];
    float* orow1 = orow0 + (size_t)16 * NN2;
    orow0[p]      = acc00.x + acc00.y + bias;
    orow0[p + 16] = acc01.x + acc01.y + bias;
    orow1[p]      = acc10.x + acc10.y + bias;
    orow1[p + 16] = acc11.x + acc11.y + bias;
}

extern "C" void kernel_launch(void* const* d_in, const int* in_sizes, int n_in,
                              void* d_out, int out_size, void* d_ws, size_t ws_size,
                              hipStream_t stream) {
    const float* x0 = (const float*)d_in[0];
    const float* x  = (const float*)d_in[1];
    const float* y  = (const float*)d_in[2];
    const float* W1 = (const float*)d_in[3];
    const float* b1 = (const float*)d_in[4];
    const float* W2 = (const float*)d_in[5];
    const float* b2 = (const float*)d_in[6];
    float* out = (float*)d_out;

    float* hx = (float*)d_ws;
    float* hy = hx + (size_t)BB * NN1 * DD;

    const int nblocks = (BB * NN1) / PR + (BB * NN2) / PR;  // 256
    proj_kernel<<<nblocks, 256, 0, stream>>>(x0, x, y, W1, b1, hx, hy);
    cross_kernel<<<dim3(NN2 / TS, NN1 / TS, BB), 256, 0, stream>>>(hx, hy, W2, b2, out);
}

// Round 8
// 41.436 us; speedup vs baseline: 1.0861x; 1.0084x over previous
//
#include <hip/hip_runtime.h>

#define BB 2
#define NN1 512
#define NN2 512
#define DD 128
#define TS 16          // cross tile: 16x16 (n,m) per block, 1 output/thread
#define SXPAD 132      // row stride in floats: 528B, b128-aligned, rows shift banks

typedef float v4f __attribute__((ext_vector_type(4)));

// ---- Trans-free GELU via degree-9 Chebyshev fit (verified R5-R7: absmax 0.0156)
struct GeluPoly {
    float p[10];
    constexpr GeluPoly() : p{} {
        const int N = 10;
        const double PI = 3.14159265358979323846;
        double fv[10] = {};
        double xv[10] = {};
        for (int j = 0; j < N; ++j) {
            double th = PI * (j + 0.5) / N;
            double cth = 1.0, term = 1.0, t2 = th * th;
            for (int k = 1; k <= 30; ++k) {
                term *= -t2 / ((2.0 * k - 1.0) * (2.0 * k));
                cth += term;
            }
            xv[j] = cth;
            double t = 4.5 * (cth + 1.0);
            double s = t > 1.0 ? t : 1.0;
            for (int it = 0; it < 64; ++it) s = 0.5 * (s + t / s);
            double x = s * 0.70710678118654752440;
            double esum = 0.0, pw = x, fact = 1.0;
            for (int k = 0; k < 48; ++k) {
                if (k > 0) { fact *= (double)k; pw *= x * x; }
                double tk = pw / (fact * (2.0 * k + 1.0));
                esum += (k & 1) ? -tk : tk;
            }
            double erfv = 1.12837916709551257390 * esum;
            fv[j] = 0.5 * erfv / s;
        }
        double ck[10] = {};
        for (int k = 0; k < N; ++k) {
            double sum = 0.0;
            for (int j = 0; j < N; ++j) {
                double Tk = 1.0;
                if (k >= 1) {
                    double Tm2 = 1.0, Tm1 = xv[j];
                    Tk = xv[j];
                    for (int i = 2; i <= k; ++i) {
                        Tk = 2.0 * xv[j] * Tm1 - Tm2;
                        Tm2 = Tm1; Tm1 = Tk;
                    }
                }
                sum += fv[j] * Tk;
            }
            ck[k] = 2.0 * sum / N;
        }
        ck[0] *= 0.5;
        double T[10][10] = {};
        T[0][0] = 1.0;
        T[1][1] = 1.0;
        for (int k = 2; k < N; ++k)
            for (int i = 0; i < N; ++i)
                T[k][i] = 2.0 * (i > 0 ? T[k - 1][i - 1] : 0.0) - T[k - 2][i];
        double pd[10] = {};
        for (int k = 0; k < N; ++k)
            for (int i = 0; i < N; ++i)
                pd[i] += ck[k] * T[k][i];
        for (int i = 0; i < N; ++i) p[i] = (float)pd[i];
    }
};
static constexpr GeluPoly GP{};

__device__ __forceinline__ float gelu_poly(float s) {
    float c = __builtin_amdgcn_fmed3f(s, -3.0f, 3.0f);
    float t = c * c;
    float u = __builtin_fmaf(t, 0.22222222222222222f, -1.0f);
    float q = GP.p[9];
    #pragma unroll
    for (int k = 8; k >= 0; --k) q = __builtin_fmaf(q, u, GP.p[k]);
    return s * __builtin_fmaf(c, q, 0.5f);
}

// Kernel 1: per-row projection, 8 rows per block, 256 threads. (unchanged)
#define PR 8
__global__ __launch_bounds__(256) void proj_kernel(
    const float* __restrict__ x0, const float* __restrict__ x,
    const float* __restrict__ y,  const float* __restrict__ W1,
    const float* __restrict__ b1, float* __restrict__ hx, float* __restrict__ hy) {
    const int e = threadIdx.x & (DD - 1);
    const int g = threadIdx.x >> 7;
    const int nxb = (BB * NN1) / PR;
    const float* Wa = W1;
    const float* Wb = W1 + DD * DD;
    const float* Wc = W1 + 2 * DD * DD;

    if (blockIdx.x < nxb) {
        const int row0 = blockIdx.x * PR + g * (PR / 2);
        float acc0 = b1[e], acc1 = b1[e], acc2 = b1[e], acc3 = b1[e];
        #pragma unroll 4
        for (int d = 0; d < DD; ++d) {
            const float wa = Wa[d * DD + e];
            const float wb = Wb[d * DD + e];
            acc0 += x0[(row0 + 0) * DD + d] * wa + x[(row0 + 0) * DD + d] * wb;
            acc1 += x0[(row0 + 1) * DD + d] * wa + x[(row0 + 1) * DD + d] * wb;
            acc2 += x0[(row0 + 2) * DD + d] * wa + x[(row0 + 2) * DD + d] * wb;
            acc3 += x0[(row0 + 3) * DD + d] * wa + x[(row0 + 3) * DD + d] * wb;
        }
        hx[(row0 + 0) * DD + e] = acc0;
        hx[(row0 + 1) * DD + e] = acc1;
        hx[(row0 + 2) * DD + e] = acc2;
        hx[(row0 + 3) * DD + e] = acc3;
    } else {
        const int row0 = (blockIdx.x - nxb) * PR + g * (PR / 2);
        float acc0 = 0.f, acc1 = 0.f, acc2 = 0.f, acc3 = 0.f;
        #pragma unroll 4
        for (int d = 0; d < DD; ++d) {
            const float wc = Wc[d * DD + e];
            acc0 += y[(row0 + 0) * DD + d] * wc;
            acc1 += y[(row0 + 1) * DD + d] * wc;
            acc2 += y[(row0 + 2) * DD + d] * wc;
            acc3 += y[(row0 + 3) * DD + d] * wc;
        }
        hy[(row0 + 0) * DD + e] = acc0;
        hy[(row0 + 1) * DD + e] = acc1;
        hy[(row0 + 2) * DD + e] = acc2;
        hy[(row0 + 3) * DD + e] = acc3;
    }
}

// Kernel 2: R1's occupancy structure (16x16 tile, 1 output/thread, 2048 blocks
// -> 8 waves/SIMD supply; R1 measured VALUBusy=100% with this shape) + cheap
// poly gelu. 4-output variants are pinned at 2 waves/SIMD and ~60% stall.
__global__ __launch_bounds__(256) void cross_kernel(
    const float* __restrict__ hx, const float* __restrict__ hy,
    const float* __restrict__ W2, const float* __restrict__ b2,
    float* __restrict__ out) {
    __shared__ float sx[TS][SXPAD];
    __shared__ float sy[TS][SXPAD];
    __shared__ float sw[DD];

    const int b  = blockIdx.z;
    const int n0 = blockIdx.y * TS;
    const int m0 = blockIdx.x * TS;
    const int tid = threadIdx.x;

    for (int i = tid; i < TS * (DD / 4); i += 256) {
        const int r  = i >> 5;
        const int c4 = i & 31;
        *(v4f*)&sx[r][c4 * 4] =
            *(const v4f*)&hx[((b * NN1) + n0 + r) * DD + c4 * 4];
        *(v4f*)&sy[r][c4 * 4] =
            *(const v4f*)&hy[((b * NN2) + m0 + r) * DD + c4 * 4];
    }
    if (tid < DD) sw[tid] = W2[tid];
    __syncthreads();

    const int tn = tid >> 4;
    const int tm = tid & 15;

    float acc = 0.0f;
    #pragma unroll 8
    for (int e4 = 0; e4 < DD / 4; ++e4) {
        const v4f a = *(const v4f*)&sx[tn][e4 * 4];
        const v4f c = *(const v4f*)&sy[tm][e4 * 4];
        const v4f w = *(const v4f*)&sw[e4 * 4];
        acc = __builtin_fmaf(gelu_poly(a.x + c.x), w.x, acc);
        acc = __builtin_fmaf(gelu_poly(a.y + c.y), w.y, acc);
        acc = __builtin_fmaf(gelu_poly(a.z + c.z), w.z, acc);
        acc = __builtin_fmaf(gelu_poly(a.w + c.w), w.w, acc);
    }

    out[((size_t)(b * NN1) + n0 + tn) * NN2 + m0 + tm] = acc + b2[0];
}

extern "C" void kernel_launch(void* const* d_in, const int* in_sizes, int n_in,
                              void* d_out, int out_size, void* d_ws, size_t ws_size,
                              hipStream_t stream) {
    const float* x0 = (const float*)d_in[0];
    const float* x  = (const float*)d_in[1];
    const float* y  = (const float*)d_in[2];
    const float* W1 = (const float*)d_in[3];
    const float* b1 = (const float*)d_in[4];
    const float* W2 = (const float*)d_in[5];
    const float* b2 = (const float*)d_in[6];
    float* out = (float*)d_out;

    float* hx = (float*)d_ws;
    float* hy = hx + (size_t)BB * NN1 * DD;

    const int nblocks = (BB * NN1) / PR + (BB * NN2) / PR;  // 256
    proj_kernel<<<nblocks, 256, 0, stream>>>(x0, x, y, W1, b1, hx, hy);
    cross_kernel<<<dim3(NN2 / TS, NN1 / TS, BB), 256, 0, stream>>>(hx, hy, W2, b2, out);
}